// Round 3
// baseline (387.354 us; speedup 1.0000x reference)
//
#include <hip/hip_runtime.h>

#define H 1024
#define S 65536

typedef float vfloat4 __attribute__((ext_vector_type(4)));

// K1a: split-K partial GEMV. Block b computes partial[b][j] = sum over its
// 8 rows of W[i][j]*h[i], j = all 1024 columns (float4 per thread).
// Plain (cached) loads: W is 4 MiB, reused every bench iteration -> L2/L3 resident.
__global__ __launch_bounds__(256) void k1a_partial(const float* __restrict__ W,
                                                   const float* __restrict__ hidden,
                                                   float* __restrict__ partial) {
    const int t = threadIdx.x;
    const int b = blockIdx.x;            // 0..127
    const int i0 = b * 8;                // 8 rows per block
    vfloat4 acc = (vfloat4)(0.f);
    #pragma unroll
    for (int r = 0; r < 8; ++r) {
        const float hv = hidden[i0 + r];             // wave-uniform broadcast
        const vfloat4 w = *(const vfloat4*)(W + (size_t)(i0 + r) * H + t * 4);
        acc += w * hv;
    }
    *(vfloat4*)(partial + (size_t)b * H + t * 4) = acc;
}

// K1b: v[j] = sum_b partial[b][j]. 4 blocks, L2-hot (512 KB).
__global__ __launch_bounds__(256) void k1b_reduce(const float* __restrict__ partial,
                                                  float* __restrict__ v) {
    const int j = blockIdx.x * 256 + threadIdx.x;
    float s0 = 0.f, s1 = 0.f;
    for (int b = 0; b < 128; b += 2) {
        s0 += partial[(size_t)b * H + j];
        s1 += partial[(size_t)(b + 1) * H + j];
    }
    v[j] = s0 + s1;
}

// K2: scores[row] = enc[row] . v, with ONLINE (m, s) softmax state per wave.
// Wave handles 2 rows/iter (8 float4 loads in flight), paired butterfly
// (7 shfl for 2 rows). Plain cached loads: enc (268 MB) can be partially
// retained by the 256 MB Infinity Cache across bench iterations.
// Grid 2048 blocks (8192 waves), 4 iters x 2 rows = 8 rows/wave.
__global__ __launch_bounds__(256) void k_scores(const float* __restrict__ enc,
                                                const float* __restrict__ v,
                                                float* __restrict__ scores,
                                                float* __restrict__ bmax,
                                                float* __restrict__ bsum) {
    const int lane = threadIdx.x & 63;
    const int warp = threadIdx.x >> 6;
    const vfloat4 vr0 = *(const vfloat4*)(v + lane * 4);
    const vfloat4 vr1 = *(const vfloat4*)(v + 256 + lane * 4);
    const vfloat4 vr2 = *(const vfloat4*)(v + 512 + lane * 4);
    const vfloat4 vr3 = *(const vfloat4*)(v + 768 + lane * 4);

    const int wg = blockIdx.x * 4 + warp;  // 0..8191
    float m = -INFINITY;                   // running max (per half-wave row stream)
    float s = 0.f;                         // running sum of exp(score - m)

    #pragma unroll
    for (int it = 0; it < 4; ++it) {
        const int r0 = wg * 2 + it * 16384;
        const int r1 = r0 + 1;
        const float* e0 = enc + (size_t)r0 * H;
        const float* e1 = enc + (size_t)r1 * H;
        const vfloat4 a0 = *(const vfloat4*)(e0 + lane * 4);
        const vfloat4 a1 = *(const vfloat4*)(e0 + 256 + lane * 4);
        const vfloat4 a2 = *(const vfloat4*)(e0 + 512 + lane * 4);
        const vfloat4 a3 = *(const vfloat4*)(e0 + 768 + lane * 4);
        const vfloat4 b0 = *(const vfloat4*)(e1 + lane * 4);
        const vfloat4 b1 = *(const vfloat4*)(e1 + 256 + lane * 4);
        const vfloat4 b2 = *(const vfloat4*)(e1 + 512 + lane * 4);
        const vfloat4 b3 = *(const vfloat4*)(e1 + 768 + lane * 4);
        const vfloat4 p0 = a0 * vr0 + a1 * vr1 + a2 * vr2 + a3 * vr3;
        const vfloat4 p1 = b0 * vr0 + b1 * vr1 + b2 * vr2 + b3 * vr3;
        float acc0 = (p0.x + p0.y) + (p0.z + p0.w);
        float acc1 = (p1.x + p1.y) + (p1.z + p1.w);
        // Fold the two rows into the two half-waves, then one 32-lane butterfly.
        const float t0 = __shfl_xor(acc0, 32, 64);
        const float t1 = __shfl_xor(acc1, 32, 64);
        float c = (lane < 32) ? (acc0 + t0) : (acc1 + t1);
        #pragma unroll
        for (int mm = 1; mm < 32; mm <<= 1) c += __shfl_xor(c, mm, 64);
        // lanes 0..31 hold sum(r0); lanes 32..63 hold sum(r1)
        if (lane == 0)  scores[r0] = c;
        if (lane == 32) scores[r1] = c;
        // online softmax update (all lanes of a half-wave carry identical state)
        const float mn = fmaxf(m, c);
        s = s * __expf(m - mn) + __expf(c - mn);
        m = mn;
    }
    // merge the two half-wave (m, s) streams
    const float mo = __shfl_xor(m, 32, 64);
    const float so = __shfl_xor(s, 32, 64);
    const float mm2 = fmaxf(m, mo);
    s = s * __expf(m - mm2) + so * __expf(mo - mm2);
    m = mm2;

    __shared__ float smx[4], ssm[4];
    if (lane == 0) { smx[warp] = m; ssm[warp] = s; }
    __syncthreads();
    if (threadIdx.x == 0) {
        const float M = fmaxf(fmaxf(smx[0], smx[1]), fmaxf(smx[2], smx[3]));
        const float SS = ssm[0] * __expf(smx[0] - M) + ssm[1] * __expf(smx[1] - M)
                       + ssm[2] * __expf(smx[2] - M) + ssm[3] * __expf(smx[3] - M);
        bmax[blockIdx.x] = M;
        bsum[blockIdx.x] = SS;
    }
}

// K_final: every block redundantly reduces bmax/bsum[2048] -> (gmax, total)
// (16 KB, L2-hot), then does the SINGLE pass: out[i] = exp(scores[i]-gmax)/total.
// Replaces the old k_exp + k_norm (saves one dispatch + one R/W of out).
__global__ __launch_bounds__(256) void k_final(const float* __restrict__ scores,
                                               const float* __restrict__ bmax,
                                               const float* __restrict__ bsum,
                                               float* __restrict__ out) {
    const int t = threadIdx.x;
    const int lane = t & 63;
    const int warp = t >> 6;

    float lm[8];
    float m = -INFINITY;
    #pragma unroll
    for (int k = 0; k < 8; ++k) {
        lm[k] = bmax[t + k * 256];
        m = fmaxf(m, lm[k]);
    }
    #pragma unroll
    for (int d = 1; d < 64; d <<= 1) m = fmaxf(m, __shfl_xor(m, d, 64));
    __shared__ float sm[4];
    if (lane == 0) sm[warp] = m;
    __syncthreads();
    const float gmax = fmaxf(fmaxf(sm[0], sm[1]), fmaxf(sm[2], sm[3]));

    float p = 0.f;
    #pragma unroll
    for (int k = 0; k < 8; ++k) p += bsum[t + k * 256] * __expf(lm[k] - gmax);
    #pragma unroll
    for (int d = 1; d < 64; d <<= 1) p += __shfl_xor(p, d, 64);
    __shared__ float sp[4];
    if (lane == 0) sp[warp] = p;
    __syncthreads();
    const float inv = 1.0f / ((sp[0] + sp[1]) + (sp[2] + sp[3]));

    const int i = blockIdx.x * 256 + t;
    out[i] = __expf(scores[i] - gmax) * inv;
}

extern "C" void kernel_launch(void* const* d_in, const int* in_sizes, int n_in,
                              void* d_out, int out_size, void* d_ws, size_t ws_size,
                              hipStream_t stream) {
    const float* hidden = (const float*)d_in[0];
    const float* enc    = (const float*)d_in[1];
    const float* W      = (const float*)d_in[2];
    // d_in[3] = b: b.hidden is a uniform shift of all scores -> softmax-invariant, dropped.
    float* out = (float*)d_out;

    float* v       = (float*)d_ws;       // 1024
    float* scores  = v + 1024;           // 65536
    float* bmax    = scores + S;         // 2048
    float* bsum    = bmax + 2048;        // 2048
    float* partial = bsum + 2048;        // 128*1024

    k1a_partial<<<128,  256, 0, stream>>>(W, hidden, partial);
    k1b_reduce <<<4,    256, 0, stream>>>(partial, v);
    k_scores   <<<2048, 256, 0, stream>>>(enc, v, scores, bmax, bsum);
    k_final    <<<256,  256, 0, stream>>>(scores, bmax, bsum, out);
}

// Round 4
// 360.679 us; speedup vs baseline: 1.0740x; 1.0740x over previous
//
#include <hip/hip_runtime.h>

#define H 1024
#define S 65536

typedef float vfloat4 __attribute__((ext_vector_type(4)));

__device__ __forceinline__ vfloat4 nt_load4(const float* p) {
    return __builtin_nontemporal_load((const vfloat4*)p);
}

// K1a: split-K partial GEMV. Block b computes partial[b][j] = sum over its
// 8 rows of W[i][j]*h[i]. NT loads: W is read once and caches are full of
// fill-poison dirt anyway -- don't allocate.
__global__ __launch_bounds__(256) void k1a_partial(const float* __restrict__ W,
                                                   const float* __restrict__ hidden,
                                                   float* __restrict__ partial) {
    const int t = threadIdx.x;
    const int b = blockIdx.x;            // 0..127
    const int i0 = b * 8;                // 8 rows per block
    vfloat4 acc = (vfloat4)(0.f);
    #pragma unroll
    for (int r = 0; r < 8; ++r) {
        const float hv = hidden[i0 + r];             // wave-uniform broadcast
        const vfloat4 w = nt_load4(W + (size_t)(i0 + r) * H + t * 4);
        acc += w * hv;
    }
    *(vfloat4*)(partial + (size_t)b * H + t * 4) = acc;  // cached: k1b re-reads from L2
}

// K1b: v[j] = sum_b partial[b][j]. 4 blocks, L2-hot (512 KB).
__global__ __launch_bounds__(256) void k1b_reduce(const float* __restrict__ partial,
                                                  float* __restrict__ v) {
    const int j = blockIdx.x * 256 + threadIdx.x;
    float s0 = 0.f, s1 = 0.f;
    for (int b = 0; b < 128; b += 2) {
        s0 += partial[(size_t)b * H + j];
        s1 += partial[(size_t)(b + 1) * H + j];
    }
    v[j] = s0 + s1;
}

// K2: scores[row] = enc[row] . v, online (m,s) softmax state per wave.
// NT loads (measured better: 359.8 vs 387.4 with cached -- the 1 GiB poison
// fill means enc is never cache-resident; allocating lines just fights the
// fill's writebacks). Register double-buffer: two row-pairs (16 KB/wave) in
// flight across the reduce+exp chain. 1024 blocks x 4 waves x 16 rows.
__global__ __launch_bounds__(256) void k_scores(const float* __restrict__ enc,
                                                const float* __restrict__ v,
                                                float* __restrict__ scores,
                                                float* __restrict__ bmax,
                                                float* __restrict__ bsum) {
    const int lane = threadIdx.x & 63;
    const int warp = threadIdx.x >> 6;
    const vfloat4 vr0 = *(const vfloat4*)(v + lane * 4);
    const vfloat4 vr1 = *(const vfloat4*)(v + 256 + lane * 4);
    const vfloat4 vr2 = *(const vfloat4*)(v + 512 + lane * 4);
    const vfloat4 vr3 = *(const vfloat4*)(v + 768 + lane * 4);

    const int wg = blockIdx.x * 4 + warp;            // 0..4095
    const float* base = enc + (size_t)(wg * 2) * H + lane * 4;  // rows r0,r1 contiguous (8 KB)

    float m = -INFINITY;   // running max (per half-wave row stream)
    float s = 0.f;         // running sum of exp(score - m)

    vfloat4 A0, A1, A2, A3, A4, A5, A6, A7;
    vfloat4 B0, B1, B2, B3, B4, B5, B6, B7;

#define LOADB(P, IT) do { \
    const float* _p = base + (size_t)(IT) * 8192 * H; \
    P##0 = nt_load4(_p);        P##1 = nt_load4(_p + 256); \
    P##2 = nt_load4(_p + 512);  P##3 = nt_load4(_p + 768); \
    P##4 = nt_load4(_p + 1024); P##5 = nt_load4(_p + 1280); \
    P##6 = nt_load4(_p + 1536); P##7 = nt_load4(_p + 1792); \
} while (0)

#define COMP(P, IT) do { \
    const vfloat4 p0 = P##0 * vr0 + P##1 * vr1 + P##2 * vr2 + P##3 * vr3; \
    const vfloat4 p1 = P##4 * vr0 + P##5 * vr1 + P##6 * vr2 + P##7 * vr3; \
    float acc0 = (p0.x + p0.y) + (p0.z + p0.w); \
    float acc1 = (p1.x + p1.y) + (p1.z + p1.w); \
    const float t0 = __shfl_xor(acc0, 32, 64); \
    const float t1 = __shfl_xor(acc1, 32, 64); \
    float c = (lane < 32) ? (acc0 + t0) : (acc1 + t1); \
    c += __shfl_xor(c, 1, 64);  c += __shfl_xor(c, 2, 64); \
    c += __shfl_xor(c, 4, 64);  c += __shfl_xor(c, 8, 64); \
    c += __shfl_xor(c, 16, 64); \
    const int _r0 = wg * 2 + (IT) * 8192; \
    if (lane == 0)  scores[_r0] = c; \
    if (lane == 32) scores[_r0 + 1] = c; \
    const float _mn = fmaxf(m, c); \
    s = s * __expf(m - _mn) + __expf(c - _mn); \
    m = _mn; \
} while (0)

    // software pipeline: always 1-2 row-pairs of NT loads in flight
    LOADB(A, 0);
    LOADB(B, 1);
    COMP(A, 0);
    LOADB(A, 2);
    COMP(B, 1);
    LOADB(B, 3);
    COMP(A, 2);
    LOADB(A, 4);
    COMP(B, 3);
    LOADB(B, 5);
    COMP(A, 4);
    LOADB(A, 6);
    COMP(B, 5);
    LOADB(B, 7);
    COMP(A, 6);
    COMP(B, 7);

#undef LOADB
#undef COMP

    // merge the two half-wave (m, s) streams
    const float mo = __shfl_xor(m, 32, 64);
    const float so = __shfl_xor(s, 32, 64);
    const float mm2 = fmaxf(m, mo);
    s = s * __expf(m - mm2) + so * __expf(mo - mm2);
    m = mm2;

    __shared__ float smx[4], ssm[4];
    if (lane == 0) { smx[warp] = m; ssm[warp] = s; }
    __syncthreads();
    if (threadIdx.x == 0) {
        const float M = fmaxf(fmaxf(smx[0], smx[1]), fmaxf(smx[2], smx[3]));
        const float SS = ssm[0] * __expf(smx[0] - M) + ssm[1] * __expf(smx[1] - M)
                       + ssm[2] * __expf(smx[2] - M) + ssm[3] * __expf(smx[3] - M);
        bmax[blockIdx.x] = M;
        bsum[blockIdx.x] = SS;
    }
}

// K_final: every block redundantly reduces bmax/bsum[1024] -> (gmax, total)
// (8 KB, L2-hot), then the SINGLE pass: out[i] = exp(scores[i]-gmax)/total.
__global__ __launch_bounds__(256) void k_final(const float* __restrict__ scores,
                                               const float* __restrict__ bmax,
                                               const float* __restrict__ bsum,
                                               float* __restrict__ out) {
    const int t = threadIdx.x;
    const int lane = t & 63;
    const int warp = t >> 6;

    float lm[4];
    float m = -INFINITY;
    #pragma unroll
    for (int k = 0; k < 4; ++k) {
        lm[k] = bmax[t + k * 256];
        m = fmaxf(m, lm[k]);
    }
    #pragma unroll
    for (int d = 1; d < 64; d <<= 1) m = fmaxf(m, __shfl_xor(m, d, 64));
    __shared__ float sm[4];
    if (lane == 0) sm[warp] = m;
    __syncthreads();
    const float gmax = fmaxf(fmaxf(sm[0], sm[1]), fmaxf(sm[2], sm[3]));

    float p = 0.f;
    #pragma unroll
    for (int k = 0; k < 4; ++k) p += bsum[t + k * 256] * __expf(lm[k] - gmax);
    #pragma unroll
    for (int d = 1; d < 64; d <<= 1) p += __shfl_xor(p, d, 64);
    __shared__ float sp[4];
    if (lane == 0) sp[warp] = p;
    __syncthreads();
    const float inv = 1.0f / ((sp[0] + sp[1]) + (sp[2] + sp[3]));

    const int i = blockIdx.x * 256 + t;
    out[i] = __expf(scores[i] - gmax) * inv;
}

extern "C" void kernel_launch(void* const* d_in, const int* in_sizes, int n_in,
                              void* d_out, int out_size, void* d_ws, size_t ws_size,
                              hipStream_t stream) {
    const float* hidden = (const float*)d_in[0];
    const float* enc    = (const float*)d_in[1];
    const float* W      = (const float*)d_in[2];
    // d_in[3] = b: b.hidden is a uniform shift of all scores -> softmax-invariant, dropped.
    float* out = (float*)d_out;

    float* v       = (float*)d_ws;       // 1024
    float* scores  = v + 1024;           // 65536
    float* bmax    = scores + S;         // 1024
    float* bsum    = bmax + 1024;        // 1024
    float* partial = bsum + 1024;        // 128*1024

    k1a_partial<<<128,  256, 0, stream>>>(W, hidden, partial);
    k1b_reduce <<<4,    256, 0, stream>>>(partial, v);
    k_scores   <<<1024, 256, 0, stream>>>(enc, v, scores, bmax, bsum);
    k_final    <<<256,  256, 0, stream>>>(scores, bmax, bsum, out);
}